// Round 2
// baseline (1714.489 us; speedup 1.0000x reference)
//
#include <hip/hip_runtime.h>
#include <hip/hip_cooperative_groups.h>
#include <math.h>

namespace cg = cooperative_groups;

#define S      384
#define SS     (S*S)
#define NE     191
#define EP     192
#define ES     (EP*S)
#define N0     192
#define MAXADJ 32

// float workspace offsets
#define OFF_W     0
#define OFF_WT    (SS)
#define OFF_BASE  (2*SS)
#define OFF_BASET (3*SS)
#define OFF_SFT   (4*SS)
#define OFF_SBT   (5*SS)
#define OFF_MSGF  (6*SS)
#define OFF_MSGB  (6*SS+ES)
#define OFF_MXF   (6*SS+2*ES)
#define OFF_MXB   (6*SS+3*ES)
#define OFF_YT    (6*SS+4*ES)
#define OFF_YT2   (6*SS+5*ES)
#define OFF_U     (6*SS+6*ES)
#define OFF_V     (OFF_U+S)
#define OFF_MAXF  (OFF_V+S)
#define OFF_MAXB  (OFF_MAXF+EP)
#define OFF_INT   (OFF_MAXB+EP)
// int region offsets (relative to int* base)
#define IOFF_DSTF 0
#define IOFF_DSTB (EP)
#define IOFF_CNTF (2*EP)
#define IOFF_CNTB (2*EP+S)
#define IOFF_ADJF (2*EP+2*S)
#define IOFF_ADJB (2*EP+2*S+S*MAXADJ)

// ---------------------------------------------------------------------------
__global__ __launch_bounds__(256) void k_setup(
    const int* __restrict__ E1f, const int* __restrict__ E1b,
    const float* __restrict__ cost, const float* __restrict__ constr,
    float* __restrict__ ws)
{
    float* W    = ws + OFF_W;    float* WT    = ws + OFF_WT;
    float* BASE = ws + OFF_BASE; float* BASET = ws + OFF_BASET;
    float* SFT  = ws + OFF_SFT;  float* SBT   = ws + OFF_SBT;
    float* MSGF = ws + OFF_MSGF; float* MSGB  = ws + OFF_MSGB;
    float* MXF  = ws + OFF_MXF;  float* MXB   = ws + OFF_MXB;
    float* U    = ws + OFF_U;    float* V     = ws + OFF_V;
    float* MAXF = ws + OFF_MAXF; float* MAXB  = ws + OFF_MAXB;
    int* ip   = (int*)(ws + OFF_INT);
    int* dstF = ip + IOFF_DSTF;  int* dstB = ip + IOFF_DSTB;
    int* cntF = ip + IOFF_CNTF;  int* cntB = ip + IOFF_CNTB;
    int* adjF = ip + IOFF_ADJF;  int* adjB = ip + IOFF_ADJB;

    int tid = blockIdx.x * 256 + threadIdx.x;
    int nt  = gridDim.x * 256;

    for (int idx = tid; idx < SS; idx += nt) {
        int i = idx / S, j = idx % S;
        float cf = (i < N0) ? ((j < N0) ? constr[i * N0 + j] : 0.f) : 1.f;
        float w  = expf(-50.f * (1.f - cf));       // exp(-LAM*(1-cf)/EPS)
        W[idx] = w; WT[j * S + i] = w;
        float ph = (i < N0 && j < N0) ? 10.f * cost[j * N0 + i] : 0.f;
        BASE[idx] = -ph;                            // sums start at 0
        BASET[j * S + i] = -ph;
        SFT[idx] = 0.f; SBT[idx] = 0.f;
    }
    for (int idx = tid; idx < ES; idx += nt) {
        MSGF[idx] = 0.f; MSGB[idx] = 0.f; MXF[idx] = 0.f;
        MXB[idx] = (idx < NE * S) ? 1.f : 0.f;      // exp(0-0)=1; pad row 0
    }
    for (int e = tid; e < EP; e += nt) {
        MAXF[e] = 0.f; MAXB[e] = 0.f;
        dstF[e] = (e < NE) ? E1f[2 * e + 1] : 0;
        dstB[e] = (e < NE) ? E1b[2 * e + 1] : 0;
    }
    for (int i = tid; i < S; i += nt) { U[i] = 0.f; V[i] = 0.f; }
    for (int s = tid; s < S; s += nt) {
        int cf_ = 0, cb_ = 0;
        for (int e = 0; e < NE; ++e) {
            if (E1f[2 * e + 1] == s && cf_ < MAXADJ) adjF[s * MAXADJ + cf_++] = e;
            if (E1b[2 * e + 1] == s && cb_ < MAXADJ) adjB[s * MAXADJ + cb_++] = e;
        }
        cntF[s] = cf_; cntB[s] = cb_;
    }
}

// ---------------------------------------------------------------------------
// half-K GEMM tile: Yout[e][s] = sum_{k in [kbeg,kbeg+192)} A[k][s] * Bm[e][k]
__device__ __forceinline__ void gemm_half(
    const float* __restrict__ A, const float* __restrict__ Bm,
    float* __restrict__ Yout, int tile, int kbeg,
    float (*la)[34], float (*lb)[34], int t)
{
    int s0 = (tile % 12) * 32;
    int e0 = (tile / 12) * 32;
    int ty = t & 15, tx = t >> 4;
    float a00 = 0.f, a01 = 0.f, a10 = 0.f, a11 = 0.f;

    for (int k0 = kbeg; k0 < kbeg + 192; k0 += 32) {
        __syncthreads();
#pragma unroll
        for (int q = t; q < 1024; q += 256) {
            int k = q >> 5, c = q & 31;
            la[k][c] = A[(k0 + k) * S + s0 + c];
        }
#pragma unroll
        for (int q = t; q < 1024; q += 256) {
            int k = q & 31, ee = q >> 5;
            lb[k][ee] = Bm[(e0 + ee) * S + k0 + k];
        }
        __syncthreads();
#pragma unroll
        for (int k = 0; k < 32; ++k) {
            float2 av = *(const float2*)&la[k][2 * ty];
            float2 bv = *(const float2*)&lb[k][2 * tx];
            a00 += av.x * bv.x; a01 += av.x * bv.y;
            a10 += av.y * bv.x; a11 += av.y * bv.y;
        }
    }
    float2 r0 = make_float2(a00, a10);
    float2 r1 = make_float2(a01, a11);
    *(float2*)&Yout[(e0 + 2 * tx)     * S + s0 + 2 * ty] = r0;
    *(float2*)&Yout[(e0 + 2 * tx + 1) * S + s0 + 2 * ty] = r1;
}

// LSE over 384 elems: rowbase[i] - sub[i], one wave (lanes 0..63)
__device__ __forceinline__ float wave_lse(
    const float* __restrict__ rowbase, const float* __restrict__ sub, int l)
{
    float x[6]; float m = -1e30f;
#pragma unroll
    for (int q = 0; q < 6; ++q) {
        int i = l + 64 * q;
        x[q] = rowbase[i] - sub[i];
        m = fmaxf(m, x[q]);
    }
#pragma unroll
    for (int off = 32; off > 0; off >>= 1) m = fmaxf(m, __shfl_xor(m, off, 64));
    float ssum = 0.f;
#pragma unroll
    for (int q = 0; q < 6; ++q) ssum += __expf(x[q] - m);
#pragma unroll
    for (int off = 32; off > 0; off >>= 1) ssum += __shfl_xor(ssum, off, 64);
    return m + __logf(ssum);
}

// per-edge-column msg update + min-reduce + Mx
__device__ __forceinline__ void msg_col(
    float* __restrict__ MSG, float* __restrict__ MX, float* __restrict__ maxOut,
    float mprev, int d, int e,
    const float* __restrict__ YT, const float* __restrict__ YT2,
    const float* __restrict__ BASET,
    const float* __restrict__ U, const float* __restrict__ V,
    float* red, int t)
{
    float ud = U[d];
    const float* bt = BASET + d * S;
    int s1 = t, s2 = t + 256;
    float y1 = YT[e * S + s1] + YT2[e * S + s1];
    float x1 = 0.5f * (MSG[e * S + s1] + ud + V[s1] - bt[s1] + mprev + __logf(y1));
    float x2 = 1e30f;
    if (s2 < S) {
        float y2 = YT[e * S + s2] + YT2[e * S + s2];
        x2 = 0.5f * (MSG[e * S + s2] + ud + V[s2] - bt[s2] + mprev + __logf(y2));
        MSG[e * S + s2] = x2;
    }
    MSG[e * S + s1] = x1;
    float mn = fminf(x1, x2);
    red[t] = mn; __syncthreads();
    for (int o = 128; o > 0; o >>= 1) {
        if (t < o) red[t] = fminf(red[t], red[t + o]);
        __syncthreads();
    }
    mn = red[0];
    MX[e * S + s1] = __expf(mn - x1);
    if (s2 < S) MX[e * S + s2] = __expf(mn - x2);
    if (t == 0) maxOut[e] = -mn;
    __syncthreads();
}

// scatter: new column-sum of msg into ST column b; update BASE/BASET by delta
__device__ __forceinline__ void scatter_col(
    const float* __restrict__ MSG, const int* __restrict__ cnt,
    const int* __restrict__ adj, float* __restrict__ ST,
    float* __restrict__ BASE, float* __restrict__ BASET, int b, int t)
{
    int c = cnt[b];
    for (int r = t; r < S; r += 256) {
        float sum = 0.f;
        for (int q = 0; q < c; ++q) sum += MSG[adj[b * MAXADJ + q] * S + r];
        float delta = sum - ST[b * S + r];
        ST[b * S + r] = sum;
        BASET[b * S + r] += delta;
        BASE[r * S + b] += delta;
    }
}

// ---------------------------------------------------------------------------
__global__ __launch_bounds__(256) void k_iter(float* __restrict__ ws,
                                              float* __restrict__ out)
{
    cg::grid_group grid = cg::this_grid();
    const int bid = blockIdx.x, t = threadIdx.x;
    const int l = t & 63, w = t >> 6;

    float* W    = ws + OFF_W;    float* WT    = ws + OFF_WT;
    float* BASE = ws + OFF_BASE; float* BASET = ws + OFF_BASET;
    float* SFT  = ws + OFF_SFT;  float* SBT   = ws + OFF_SBT;
    float* MSGF = ws + OFF_MSGF; float* MSGB  = ws + OFF_MSGB;
    float* MXF  = ws + OFF_MXF;  float* MXB   = ws + OFF_MXB;
    float* YT   = ws + OFF_YT;   float* YT2   = ws + OFF_YT2;
    float* U    = ws + OFF_U;    float* V     = ws + OFF_V;
    float* MAXF = ws + OFF_MAXF; float* MAXB  = ws + OFF_MAXB;
    int* ip   = (int*)(ws + OFF_INT);
    int* dstF = ip + IOFF_DSTF;  int* dstB = ip + IOFF_DSTB;
    int* cntF = ip + IOFF_CNTF;  int* cntB = ip + IOFF_CNTB;
    int* adjF = ip + IOFF_ADJF;  int* adjB = ip + IOFF_ADJB;

    __shared__ float la[32][34];
    __shared__ float lb[32][34];
    __shared__ float red[256];

    for (int step = 0; step < 8; ++step) {
        // ---- P1: GEMM_f (K-split over 144 blocks) || u-phase ----
        if (bid < 72)        gemm_half(W, MXB, YT,  bid,       0, la, lb, t);
        else if (bid < 144)  gemm_half(W, MXB, YT2, bid - 72, 192, la, lb, t);
        else {
            int j = (bid - 144) * 4 + w;
            if (j < S) {
                float r = wave_lse(BASET + j * S, V, l);
                if (l == 0) U[j] = r;
            }
        }
        grid.sync();

        // ---- P2: v-phase ----
        {
            int i = bid * 4 + w;
            if (i < S) {
                float r = wave_lse(BASE + i * S, U, l);
                if (l == 0) V[i] = r;
            }
        }
        grid.sync();

        // ---- P3: msg_f column update ----
        if (bid < NE)
            msg_col(MSGF, MXF, MAXF, MAXB[bid], dstF[bid], bid,
                    YT, YT2, BASET, U, V, red, t);
        grid.sync();

        // ---- P4: GEMM_b || scatter_f (updates SFT, BASE, BASET) ----
        if (bid < 72)        gemm_half(WT, MXF, YT,  bid,       0, la, lb, t);
        else if (bid < 144)  gemm_half(WT, MXF, YT2, bid - 72, 192, la, lb, t);
        else
            for (int b = bid - 144; b < S; b += 112)
                scatter_col(MSGF, cntF, adjF, SFT, BASE, BASET, b, t);
        grid.sync();

        // ---- P5: msg_b column update ----
        if (bid < NE)
            msg_col(MSGB, MXB, MAXB, MAXF[bid], dstB[bid], bid,
                    YT, YT2, BASET, U, V, red, t);
        grid.sync();

        // ---- P6: scatter_b ----
        for (int b = bid; b < S; b += 256)
            scatter_col(MSGB, cntB, adjB, SBT, BASE, BASET, b, t);
        grid.sync();
    }

    // ---- finalize: out[a][b] = exp(min(BASET[a][b] - U[a] - V[b], 0)) ----
    for (int idx = bid * 256 + t; idx < SS; idx += 256 * 256) {
        int a = idx / S, b2 = idx - a * S;
        out[idx] = __expf(fminf(BASET[idx] - U[a] - V[b2], 0.f));
    }
}

// ---------------------------------------------------------------------------
extern "C" void kernel_launch(void* const* d_in, const int* in_sizes, int n_in,
                              void* d_out, int out_size, void* d_ws, size_t ws_size,
                              hipStream_t stream)
{
    const int*   E1f    = (const int*)d_in[0];
    const int*   E1b    = (const int*)d_in[1];
    const float* cost   = (const float*)d_in[3];
    const float* constr = (const float*)d_in[4];

    float* ws   = (float*)d_ws;
    float* outp = (float*)d_out;

    k_setup<<<256, 256, 0, stream>>>(E1f, E1b, cost, constr, ws);

    void* args[] = { (void*)&ws, (void*)&outp };
    hipLaunchCooperativeKernel((const void*)k_iter, dim3(256), dim3(256),
                               args, 0, stream);
}

// Round 3
// 1097.731 us; speedup vs baseline: 1.5618x; 1.5618x over previous
//
#include <hip/hip_runtime.h>
#include <math.h>

#define S      384
#define N0     192
#define NE     191
#define EP     192
#define MAXADJ 16
#define E50    1.9287498e-22f   // exp(-50)

// float workspace offsets
#define OFF_W     0
#define OFF_WT    36864
#define OFF_GF    73728
#define OFF_GB    110592
#define OFF_MSGF  147456
#define OFF_MSGB  221184
#define OFF_MXF   294912
#define OFF_MXB   368640
#define OFF_SFT   442368
#define OFF_SBT   516096
#define OFF_BASET 589824
#define OFF_U     663552
#define OFF_V     663936
#define OFF_MAXF  664320
#define OFF_MAXB  664512
#define OFF_HIB   664704
#define OFF_LOB   664896
#define OFF_HIF   665088
#define OFF_LOF   665280
#define OFF_INT   665472
// int offsets relative to (int*)(ws + OFF_INT)
#define IOFF_DSTF 0
#define IOFF_DSTB 192
#define IOFF_CNTF 384
#define IOFF_CNTB 576
#define IOFF_ADJF 768
#define IOFF_ADJB (768 + 192*MAXADJ)

// ---------------------------------------------------------------------------
__global__ __launch_bounds__(256) void k_setup(
    const int* __restrict__ E1f, const int* __restrict__ E1b,
    const float* __restrict__ cost, const float* __restrict__ constr,
    float* __restrict__ ws)
{
    int tid = blockIdx.x * 256 + threadIdx.x;
    int nt  = gridDim.x * 256;

    // W192[k][s] = exp(-50*(1-constr[k][s])); WT[k][s] = exp(-50*(1-constr[s][k]))
    for (int idx = tid; idx < 192 * 192; idx += nt) {
        int k = idx / 192, s = idx % 192;
        float w = __expf(-50.f * (1.f - constr[idx]));
        ws[OFF_W + idx] = w;
        ws[OFF_WT + s * 192 + k] = w;
    }
    for (int idx = tid; idx < EP * S; idx += nt) {
        int e = idx / S, i = idx % S;
        ws[OFF_MSGF + idx] = 0.f;
        ws[OFF_MSGB + idx] = 0.f;
        ws[OFF_MXF + idx]  = 0.f;
        ws[OFF_MXB + idx]  = (e < NE) ? 1.f : 0.f;   // exp(0-0)=1, pad row 0
        ws[OFF_SFT + idx]  = 0.f;
        ws[OFF_SBT + idx]  = 0.f;
        // BASET[b][i] = -PHIE[i][b] = -10*cost[b][i] for i<192 else 0
        ws[OFF_BASET + idx] = (i < N0) ? -10.f * cost[e * N0 + i] : 0.f;
    }
    for (int i = tid; i < S; i += nt) { ws[OFF_U + i] = 0.f; ws[OFF_V + i] = 0.f; }

    int* ip = (int*)(ws + OFF_INT);
    for (int e = tid; e < 192; e += nt) {
        ws[OFF_MAXF + e] = 0.f; ws[OFF_MAXB + e] = 0.f;
        ws[OFF_HIB + e] = 0.f;  ws[OFF_LOB + e] = 0.f;
        ws[OFF_HIF + e] = 0.f;  ws[OFF_LOF + e] = 0.f;
        ip[IOFF_DSTF + e] = (e < NE) ? E1f[2 * e + 1] : 0;
        ip[IOFF_DSTB + e] = (e < NE) ? E1b[2 * e + 1] : 0;
    }
    for (int b = tid; b < 192; b += nt) {
        int cf = 0, cb = 0;
        for (int e = 0; e < NE; ++e) {
            if (E1f[2 * e + 1] == b && cf < MAXADJ) ip[IOFF_ADJF + b * MAXADJ + cf++] = e;
            if (E1b[2 * e + 1] == b && cb < MAXADJ) ip[IOFF_ADJB + b * MAXADJ + cb++] = e;
        }
        ip[IOFF_CNTF + b] = cf;
        ip[IOFF_CNTB + b] = cb;
    }
}

// ---------------------------------------------------------------------------
// 32x32 GEMM tile: G[e][s] = sum_{k<192} A[k][s] * Bm[e][k]
__device__ __forceinline__ void gemm_blk(
    const float* __restrict__ A, const float* __restrict__ Bm,
    float* __restrict__ G, int tile, int t,
    float (*la)[34], float (*lb)[34])
{
    int s0 = (tile % 6) * 32, e0 = (tile / 6) * 32;
    int ty = t & 15, tx = t >> 4;
    float a00 = 0.f, a01 = 0.f, a10 = 0.f, a11 = 0.f;

    for (int k0 = 0; k0 < 192; k0 += 32) {
        __syncthreads();
#pragma unroll
        for (int q = t; q < 1024; q += 256) {
            int k = q >> 5, c = q & 31;
            la[k][c] = A[(k0 + k) * 192 + s0 + c];
        }
#pragma unroll
        for (int q = t; q < 1024; q += 256) {
            int k = q & 31, e = q >> 5;
            lb[k][e] = Bm[(e0 + e) * S + k0 + k];
        }
        __syncthreads();
#pragma unroll
        for (int k = 0; k < 32; ++k) {
            float2 av = *(const float2*)&la[k][2 * ty];
            float2 bv = *(const float2*)&lb[k][2 * tx];
            a00 += av.x * bv.x; a01 += av.x * bv.y;
            a10 += av.y * bv.x; a11 += av.y * bv.y;
        }
    }
    *(float2*)&G[(e0 + 2 * tx)     * 192 + s0 + 2 * ty] = make_float2(a00, a10);
    *(float2*)&G[(e0 + 2 * tx + 1) * 192 + s0 + 2 * ty] = make_float2(a01, a11);
}

// column sums of MX: LO[e] = sum_{k<192} MX[e][k], HI[e] = sum_{k>=192}
__device__ __forceinline__ void colsum_blk(
    const float* __restrict__ MX, float* __restrict__ HI, float* __restrict__ LO, int t)
{
    int l = t & 63, w = t >> 6;
    for (int e = w; e < NE; e += 4) {
        const float* row = MX + e * S;
        float lo = row[l] + row[l + 64] + row[l + 128];
        float hi = row[l + 192] + row[l + 256] + row[l + 320];
#pragma unroll
        for (int o = 32; o; o >>= 1) {
            lo += __shfl_xor(lo, o, 64);
            hi += __shfl_xor(hi, o, 64);
        }
        if (l == 0) { LO[e] = lo; HI[e] = hi; }
    }
}

// u then v, single block of 256 threads
__device__ __forceinline__ void uv_block(float* __restrict__ ws, int t,
                                         float* red, float* uSm)
{
    float* U = ws + OFF_U;
    float* V = ws + OFF_V;
    const float* BT = ws + OFF_BASET;
    int l = t & 63, w = t >> 6;

    // u[j] = LSE_i(BASET[j][i] - V[i]) for j<192
    float vloc[6];
#pragma unroll
    for (int q = 0; q < 6; ++q) vloc[q] = V[l + 64 * q];

    for (int j = w; j < 192; j += 4) {
        const float* row = BT + j * S;
        float x[6], m = -1e30f;
#pragma unroll
        for (int q = 0; q < 6; ++q) {
            x[q] = row[l + 64 * q] - vloc[q];
            m = fmaxf(m, x[q]);
        }
#pragma unroll
        for (int o = 32; o; o >>= 1) m = fmaxf(m, __shfl_xor(m, o, 64));
        float sm = 0.f;
#pragma unroll
        for (int q = 0; q < 6; ++q) sm += __expf(x[q] - m);
#pragma unroll
        for (int o = 32; o; o >>= 1) sm += __shfl_xor(sm, o, 64);
        if (l == 0) { float r = m + __logf(sm); U[j] = r; uSm[j] = r; }
    }

    // u_hi = LSE_i(-V[i])
    float a1 = -V[t];
    float a2 = (t < 128) ? -V[t + 256] : -1e30f;
    red[t] = fmaxf(a1, a2);
    __syncthreads();
    for (int o = 128; o; o >>= 1) {
        if (t < o) red[t] = fmaxf(red[t], red[t + o]);
        __syncthreads();
    }
    float M = red[0];
    __syncthreads();
    red[t] = __expf(a1 - M) + ((t < 128) ? __expf(a2 - M) : 0.f);
    __syncthreads();
    for (int o = 128; o; o >>= 1) {
        if (t < o) red[t] += red[t + o];
        __syncthreads();
    }
    float uhi = M + __logf(red[0]);
    __syncthreads();
    if (t < 192) U[192 + t] = uhi;
    __syncthreads();

    // v[i] = log( sum_{j<192} exp(BASET[j][i]-u[j]) + 192*exp(-uhi) )
    float xe = __logf(192.f) - uhi;
    for (int i = t; i < S; i += 256) {
        float m = xe;
        for (int j = 0; j < 192; ++j)
            m = fmaxf(m, BT[j * S + i] - uSm[j]);
        float sm = __expf(xe - m);
        for (int j = 0; j < 192; ++j)
            sm += __expf(BT[j * S + i] - uSm[j] - m);
        V[i] = m + __logf(sm);
    }
}

// scatter new column sums of MSG into ST rows; update BASET by delta
__device__ __forceinline__ void scatter_cols(
    const float* __restrict__ MSG, const int* __restrict__ cnt,
    const int* __restrict__ adj, float* __restrict__ ST,
    float* __restrict__ BT, int b, int t)
{
    int c = cnt[b];
    if (c == 0) return;
    for (int r = t; r < S; r += 256) {
        float sum = 0.f;
        for (int q = 0; q < c; ++q)
            sum += MSG[adj[b * MAXADJ + q] * S + r];
        float old = ST[b * S + r];
        ST[b * S + r] = sum;
        BT[b * S + r] += sum - old;
    }
}

// ---------------------------------------------------------------------------
// K1: GEMM_f (36 blocks) || colsum_b (1) || uv (1)
__global__ __launch_bounds__(256) void k_fwd_pre(float* __restrict__ ws)
{
    __shared__ float la[32][34], lb[32][34];
    __shared__ float red[256];
    __shared__ float uSm[192];
    int bid = blockIdx.x, t = threadIdx.x;
    if (bid < 36)
        gemm_blk(ws + OFF_W, ws + OFF_MXB, ws + OFF_GF, bid, t, la, lb);
    else if (bid == 36)
        colsum_blk(ws + OFF_MXB, ws + OFF_HIB, ws + OFF_LOB, t);
    else
        uv_block(ws, t, red, uSm);
}

// K3: GEMM_b (36) || colsum_f (1) || scatter_f (12)
__global__ __launch_bounds__(256) void k_bwd_pre(float* __restrict__ ws)
{
    __shared__ float la[32][34], lb[32][34];
    int bid = blockIdx.x, t = threadIdx.x;
    int* ip = (int*)(ws + OFF_INT);
    if (bid < 36)
        gemm_blk(ws + OFF_WT, ws + OFF_MXF, ws + OFF_GB, bid, t, la, lb);
    else if (bid == 36)
        colsum_blk(ws + OFF_MXF, ws + OFF_HIF, ws + OFF_LOF, t);
    else
        for (int b = bid - 37; b < 192; b += 12)
            scatter_cols(ws + OFF_MSGF, ip + IOFF_CNTF, ip + IOFF_ADJF,
                         ws + OFF_SFT, ws + OFF_BASET, b, t);
}

// K2/K4: msg update, one block per edge
__global__ __launch_bounds__(256) void k_msg(float* __restrict__ ws, int fwd)
{
    __shared__ float red[256];
    int e = blockIdx.x, t = threadIdx.x;
    int* ip = (int*)(ws + OFF_INT);

    float* MSG = ws + (fwd ? OFF_MSGF : OFF_MSGB);
    float* MX  = ws + (fwd ? OFF_MXF  : OFF_MXB);
    float* MAXo = ws + (fwd ? OFF_MAXF : OFF_MAXB);
    const float* G = ws + (fwd ? OFF_GF : OFF_GB);
    const int* dst = ip + (fwd ? IOFF_DSTF : IOFF_DSTB);

    float mPrev = fwd ? ws[OFF_MAXB + e] : ws[OFF_MAXF + e];
    float hi    = fwd ? ws[OFF_HIB + e] : ws[OFF_HIF + e];
    float lo    = fwd ? ws[OFF_LOB + e] : ws[OFF_LOF + e];
    float addLo = fwd ? hi : E50 * hi;              // added to G for s<192
    float yHi   = fwd ? (hi + E50 * lo) : (lo + hi); // Y for s>=192
    float lyHi  = __logf(yHi);

    int d = dst[e];
    float uD = ws[OFF_U + d];
    const float* bt = ws + OFF_BASET + d * S;
    const float* V = ws + OFF_V;

    int s1 = t, s2 = t + 256;
    float logy1 = (s1 < 192) ? __logf(G[e * 192 + s1] + addLo) : lyHi;
    float x1 = 0.5f * (MSG[e * S + s1] + uD + V[s1] - bt[s1] + mPrev + logy1);
    float x2 = 1e30f;
    if (s2 < S) {
        x2 = 0.5f * (MSG[e * S + s2] + uD + V[s2] - bt[s2] + mPrev + lyHi);
        MSG[e * S + s2] = x2;
    }
    MSG[e * S + s1] = x1;

    red[t] = fminf(x1, x2);
    __syncthreads();
    for (int o = 128; o; o >>= 1) {
        if (t < o) red[t] = fminf(red[t], red[t + o]);
        __syncthreads();
    }
    float mn = red[0];

    MX[e * S + s1] = __expf(mn - x1);
    if (s2 < S) MX[e * S + s2] = __expf(mn - x2);
    if (t == 0) MAXo[e] = -mn;
}

// K5: scatter_b (12 blocks)
__global__ __launch_bounds__(256) void k_scatter_b(float* __restrict__ ws)
{
    int t = threadIdx.x;
    int* ip = (int*)(ws + OFF_INT);
    for (int b = blockIdx.x; b < 192; b += 12)
        scatter_cols(ws + OFF_MSGB, ip + IOFF_CNTB, ip + IOFF_ADJB,
                     ws + OFF_SBT, ws + OFF_BASET, b, t);
}

// final: out[a][b] = exp(min(BASET[a][b] - U[a] - V[b], 0)), BASET=0 for a>=192
__global__ __launch_bounds__(256) void k_final(const float* __restrict__ ws,
                                               float* __restrict__ out)
{
    int a = blockIdx.x, t = threadIdx.x;
    float ua = ws[OFF_U + a];
    const float* V = ws + OFF_V;
    const float* bt = ws + OFF_BASET + a * S;
    for (int b = t; b < S; b += 256) {
        float base = (a < 192) ? bt[b] : 0.f;
        out[a * S + b] = __expf(fminf(base - ua - V[b], 0.f));
    }
}

// ---------------------------------------------------------------------------
extern "C" void kernel_launch(void* const* d_in, const int* in_sizes, int n_in,
                              void* d_out, int out_size, void* d_ws, size_t ws_size,
                              hipStream_t stream)
{
    const int*   E1f    = (const int*)d_in[0];
    const int*   E1b    = (const int*)d_in[1];
    const float* cost   = (const float*)d_in[3];
    const float* constr = (const float*)d_in[4];

    float* ws = (float*)d_ws;

    k_setup<<<64, 256, 0, stream>>>(E1f, E1b, cost, constr, ws);

    for (int step = 0; step < 8; ++step) {
        k_fwd_pre<<<38, 256, 0, stream>>>(ws);
        k_msg<<<NE, 256, 0, stream>>>(ws, 1);
        k_bwd_pre<<<49, 256, 0, stream>>>(ws);
        k_msg<<<NE, 256, 0, stream>>>(ws, 0);
        k_scatter_b<<<12, 256, 0, stream>>>(ws);
    }

    k_final<<<S, 256, 0, stream>>>(ws, (float*)d_out);
}

// Round 4
// 532.485 us; speedup vs baseline: 3.2198x; 2.0615x over previous
//
#include <hip/hip_runtime.h>
#include <math.h>

#define S      384
#define N0     192
#define NE     191
#define EP     192
#define MAXADJ 16
#define E50    1.9287498e-22f   // exp(-50)

// float workspace offsets
#define OFF_W     0
#define OFF_WT    36864
#define OFF_GF    73728
#define OFF_GB    110592
#define OFF_MSGF  147456
#define OFF_MSGB  221184
#define OFF_MXF   294912
#define OFF_MXB   368640
#define OFF_SFT   442368
#define OFF_SBT   516096
#define OFF_BASET 589824
#define OFF_U     663552
#define OFF_V     663936
#define OFF_MAXF  664320
#define OFF_MAXB  664512
#define OFF_HIB   664704
#define OFF_LOB   664896
#define OFF_HIF   665088
#define OFF_LOF   665280
#define OFF_UHI   665472
#define OFF_INT   665536
// int offsets relative to (int*)(ws + OFF_INT)
#define IOFF_DSTF 0
#define IOFF_DSTB 192
#define IOFF_CNTF 384
#define IOFF_CNTB 576
#define IOFF_ADJF 768
#define IOFF_ADJB (768 + 192*MAXADJ)

// ---------------------------------------------------------------------------
__global__ __launch_bounds__(256) void k_setup(
    const int* __restrict__ E1f, const int* __restrict__ E1b,
    const float* __restrict__ cost, const float* __restrict__ constr,
    float* __restrict__ ws)
{
    int tid = blockIdx.x * 256 + threadIdx.x;
    int nt  = gridDim.x * 256;

    for (int idx = tid; idx < 192 * 192; idx += nt) {
        int k = idx / 192, s = idx % 192;
        float w = __expf(-50.f * (1.f - constr[idx]));
        ws[OFF_W + idx] = w;
        ws[OFF_WT + s * 192 + k] = w;
    }
    for (int idx = tid; idx < EP * S; idx += nt) {
        int e = idx / S, i = idx % S;
        ws[OFF_MSGF + idx] = 0.f;
        ws[OFF_MSGB + idx] = 0.f;
        ws[OFF_MXF + idx]  = 0.f;
        ws[OFF_MXB + idx]  = (e < NE) ? 1.f : 0.f;   // exp(0-0)=1, pad row
        ws[OFF_SFT + idx]  = 0.f;
        ws[OFF_SBT + idx]  = 0.f;
        ws[OFF_BASET + idx] = (i < N0) ? -10.f * cost[e * N0 + i] : 0.f;
    }
    for (int i = tid; i < S; i += nt) { ws[OFF_U + i] = 0.f; ws[OFF_V + i] = 0.f; }
    if (tid == 0) ws[OFF_UHI] = 0.f;

    int* ip = (int*)(ws + OFF_INT);
    for (int e = tid; e < 192; e += nt) {
        ws[OFF_MAXF + e] = 0.f; ws[OFF_MAXB + e] = 0.f;
        ws[OFF_HIB + e] = (e < NE) ? 192.f : 0.f;   // colsums of MXB init (all 1)
        ws[OFF_LOB + e] = (e < NE) ? 192.f : 0.f;
        ws[OFF_HIF + e] = 0.f;  ws[OFF_LOF + e] = 0.f;
        ip[IOFF_DSTF + e] = (e < NE) ? E1f[2 * e + 1] : 0;
        ip[IOFF_DSTB + e] = (e < NE) ? E1b[2 * e + 1] : 0;
    }
    for (int b = tid; b < 192; b += nt) {
        int cf = 0, cb = 0;
        for (int e = 0; e < NE; ++e) {
            if (E1f[2 * e + 1] == b && cf < MAXADJ) ip[IOFF_ADJF + b * MAXADJ + cf++] = e;
            if (E1b[2 * e + 1] == b && cb < MAXADJ) ip[IOFF_ADJB + b * MAXADJ + cb++] = e;
        }
        ip[IOFF_CNTF + b] = cf;
        ip[IOFF_CNTB + b] = cb;
    }
}

// ---------------------------------------------------------------------------
// 32x32 GEMM tile: G[e][s] = sum_{k<192} A[k][s] * Bm[e][k]
__device__ __forceinline__ void gemm_blk(
    const float* __restrict__ A, const float* __restrict__ Bm,
    float* __restrict__ G, int tile, int t,
    float (*la)[34], float (*lb)[34])
{
    int s0 = (tile % 6) * 32, e0 = (tile / 6) * 32;
    int ty = t & 15, tx = t >> 4;
    float a00 = 0.f, a01 = 0.f, a10 = 0.f, a11 = 0.f;

    for (int k0 = 0; k0 < 192; k0 += 32) {
        __syncthreads();
#pragma unroll
        for (int q = t; q < 1024; q += 256) {
            int k = q >> 5, c = q & 31;
            la[k][c] = A[(k0 + k) * 192 + s0 + c];
        }
#pragma unroll
        for (int q = t; q < 1024; q += 256) {
            int k = q & 31, e = q >> 5;
            lb[k][e] = Bm[(e0 + e) * S + k0 + k];
        }
        __syncthreads();
#pragma unroll
        for (int k = 0; k < 32; ++k) {
            float2 av = *(const float2*)&la[k][2 * ty];
            float2 bv = *(const float2*)&lb[k][2 * tx];
            a00 += av.x * bv.x; a01 += av.x * bv.y;
            a10 += av.y * bv.x; a11 += av.y * bv.y;
        }
    }
    *(float2*)&G[(e0 + 2 * tx)     * 192 + s0 + 2 * ty] = make_float2(a00, a10);
    *(float2*)&G[(e0 + 2 * tx + 1) * 192 + s0 + 2 * ty] = make_float2(a01, a11);
}

// scatter new column sums of MSG into ST rows; update BASET by delta
__device__ __forceinline__ void scatter_cols(
    const float* __restrict__ MSG, const int* __restrict__ cnt,
    const int* __restrict__ adj, float* __restrict__ ST,
    float* __restrict__ BT, int b, int t)
{
    int c = cnt[b];
    if (c == 0) return;
    for (int r = t; r < S; r += 256) {
        float sum = 0.f;
        for (int q = 0; q < c; ++q)
            sum += MSG[adj[b * MAXADJ + q] * S + r];
        float old = ST[b * S + r];
        ST[b * S + r] = sum;
        BT[b * S + r] += sum - old;
    }
}

// ---------------------------------------------------------------------------
// A: GEMM_f (blocks 0..35) || u-LSE (blocks 36..41)
__global__ __launch_bounds__(256) void k_phase_a(float* __restrict__ ws)
{
    __shared__ float la[32][34], lb[32][34];
    int bid = blockIdx.x, t = threadIdx.x;

    if (bid < 36) {
        gemm_blk(ws + OFF_W, ws + OFF_MXB, ws + OFF_GF, bid, t, la, lb);
        return;
    }
    // u[j] = LSE_i(BT[j][i] - V[i]) over all 384 i, for j in [ub*32, ub*32+32)
    int ub = bid - 36;
    int l = t & 63, w = t >> 6;
    const float* BT = ws + OFF_BASET;
    const float* V  = ws + OFF_V;
    float* U = ws + OFF_U;

    float vloc[6];
#pragma unroll
    for (int q = 0; q < 6; ++q) vloc[q] = V[l + 64 * q];

    for (int j = ub * 32 + w; j < ub * 32 + 32; j += 4) {
        const float* row = BT + j * S;
        float x[6], m = -1e30f;
#pragma unroll
        for (int q = 0; q < 6; ++q) {
            x[q] = row[l + 64 * q] - vloc[q];
            m = fmaxf(m, x[q]);
        }
#pragma unroll
        for (int o = 32; o; o >>= 1) m = fmaxf(m, __shfl_xor(m, o, 64));
        float sm = 0.f;
#pragma unroll
        for (int q = 0; q < 6; ++q) sm += __expf(x[q] - m);
#pragma unroll
        for (int o = 32; o; o >>= 1) sm += __shfl_xor(sm, o, 64);
        if (l == 0) U[j] = m + __logf(sm);
    }
    // uhi = LSE_i(-V[i])   (one wave of block 36)
    if (ub == 0 && w == 0) {
        float m = -1e30f;
#pragma unroll
        for (int q = 0; q < 6; ++q) m = fmaxf(m, -vloc[q]);
#pragma unroll
        for (int o = 32; o; o >>= 1) m = fmaxf(m, __shfl_xor(m, o, 64));
        float sm = 0.f;
#pragma unroll
        for (int q = 0; q < 6; ++q) sm += __expf(-vloc[q] - m);
#pragma unroll
        for (int o = 32; o; o >>= 1) sm += __shfl_xor(sm, o, 64);
        if (l == 0) ws[OFF_UHI] = m + __logf(sm);
    }
}

// B: v[i] = log( sum_{j<192} exp(BT[j][i]-u[j]) + 192*exp(-uhi) ), 12 blocks x 32 i
__global__ __launch_bounds__(256) void k_v(float* __restrict__ ws)
{
    __shared__ float Ul[192];
    __shared__ float msh[8][36], ssh[8][36];
    int t = threadIdx.x, bid = blockIdx.x;
    if (t < 192) Ul[t] = ws[OFF_U + t];
    __syncthreads();

    const float* BT = ws + OFF_BASET;
    int il = t & 31, jg = t >> 5;
    int i = bid * 32 + il;

    float m = -1e30f, sm = 0.f;
#pragma unroll 4
    for (int j = jg; j < 192; j += 8) {
        float x = BT[j * S + i] - Ul[j];
        float mn = fmaxf(m, x);
        sm = sm * __expf(m - mn) + __expf(x - mn);
        m = mn;
    }
    msh[jg][il] = m; ssh[jg][il] = sm;
    __syncthreads();

    if (jg == 0) {
        float M = msh[0][il], Ss = ssh[0][il];
#pragma unroll
        for (int g = 1; g < 8; ++g) {
            float m2 = msh[g][il], s2 = ssh[g][il];
            float mn = fmaxf(M, m2);
            Ss = Ss * __expf(M - mn) + s2 * __expf(m2 - mn);
            M = mn;
        }
        float xt = __logf(192.f) - ws[OFF_UHI];
        float mn = fmaxf(M, xt);
        Ss = Ss * __expf(M - mn) + __expf(xt - mn);
        ws[OFF_V + i] = mn + __logf(Ss);
    }
}

// C/E: msg update + own colsum, one block per edge
__global__ __launch_bounds__(256) void k_msg(float* __restrict__ ws, int fwd)
{
    __shared__ float red[256], red2[256];
    int e = blockIdx.x, t = threadIdx.x;
    int* ip = (int*)(ws + OFF_INT);

    float* MSG  = ws + (fwd ? OFF_MSGF : OFF_MSGB);
    float* MX   = ws + (fwd ? OFF_MXF  : OFF_MXB);
    float* MAXo = ws + (fwd ? OFF_MAXF : OFF_MAXB);
    float* LOo  = ws + (fwd ? OFF_LOF  : OFF_LOB);
    float* HIo  = ws + (fwd ? OFF_HIF  : OFF_HIB);
    const float* G = ws + (fwd ? OFF_GF : OFF_GB);
    const int* dst = ip + (fwd ? IOFF_DSTF : IOFF_DSTB);

    float mPrev = fwd ? ws[OFF_MAXB + e] : ws[OFF_MAXF + e];
    float hi    = fwd ? ws[OFF_HIB + e] : ws[OFF_HIF + e];
    float lo    = fwd ? ws[OFF_LOB + e] : ws[OFF_LOF + e];
    float addLo = fwd ? hi : E50 * hi;               // add to G for s<192
    float yHi   = fwd ? (hi + E50 * lo) : (lo + hi); // Y for s>=192
    float lyHi  = __logf(yHi);

    int d = dst[e];
    float uD = ws[OFF_U + d];
    const float* bt = ws + OFF_BASET + d * S;
    const float* V = ws + OFF_V;

    int s1 = t, s2 = t + 256;
    float logy1 = (s1 < 192) ? __logf(G[e * 192 + s1] + addLo) : lyHi;
    float x1 = 0.5f * (MSG[e * S + s1] + uD + V[s1] - bt[s1] + mPrev + logy1);
    float x2 = 1e30f;
    if (s2 < S) {
        x2 = 0.5f * (MSG[e * S + s2] + uD + V[s2] - bt[s2] + mPrev + lyHi);
        MSG[e * S + s2] = x2;
    }
    MSG[e * S + s1] = x1;

    red[t] = fminf(x1, x2);
    __syncthreads();
    for (int o = 128; o; o >>= 1) {
        if (t < o) red[t] = fminf(red[t], red[t + o]);
        __syncthreads();
    }
    float mn = red[0];
    __syncthreads();

    float mx1 = __expf(mn - x1);
    float mx2 = (s2 < S) ? __expf(mn - x2) : 0.f;
    MX[e * S + s1] = mx1;
    if (s2 < S) MX[e * S + s2] = mx2;
    if (t == 0) MAXo[e] = -mn;

    // fused colsum: lo = sum_{s<192} MX, hi = sum_{s>=192} MX
    red[t]  = (t < 192) ? mx1 : 0.f;
    red2[t] = ((t >= 192) ? mx1 : 0.f) + mx2;
    __syncthreads();
    for (int o = 128; o; o >>= 1) {
        if (t < o) { red[t] += red[t + o]; red2[t] += red2[t + o]; }
        __syncthreads();
    }
    if (t == 0) { LOo[e] = red[0]; HIo[e] = red2[0]; }
}

// D: GEMM_b (blocks 0..35) || scatter_f (blocks 36..47)
__global__ __launch_bounds__(256) void k_phase_d(float* __restrict__ ws)
{
    __shared__ float la[32][34], lb[32][34];
    int bid = blockIdx.x, t = threadIdx.x;
    int* ip = (int*)(ws + OFF_INT);
    if (bid < 36)
        gemm_blk(ws + OFF_WT, ws + OFF_MXF, ws + OFF_GB, bid, t, la, lb);
    else
        for (int b = bid - 36; b < 192; b += 12)
            scatter_cols(ws + OFF_MSGF, ip + IOFF_CNTF, ip + IOFF_ADJF,
                         ws + OFF_SFT, ws + OFF_BASET, b, t);
}

// F: scatter_b (12 blocks)
__global__ __launch_bounds__(256) void k_scatter_b(float* __restrict__ ws)
{
    int t = threadIdx.x;
    int* ip = (int*)(ws + OFF_INT);
    for (int b = blockIdx.x; b < 192; b += 12)
        scatter_cols(ws + OFF_MSGB, ip + IOFF_CNTB, ip + IOFF_ADJB,
                     ws + OFF_SBT, ws + OFF_BASET, b, t);
}

// final: out[a][b] = exp(min(BT[a][b] - U[a] - V[b], 0)); BT row = 0, U = uhi for a>=192
__global__ __launch_bounds__(256) void k_final(const float* __restrict__ ws,
                                               float* __restrict__ out)
{
    int a = blockIdx.x, t = threadIdx.x;
    float ua = (a < 192) ? ws[OFF_U + a] : ws[OFF_UHI];
    const float* V = ws + OFF_V;
    const float* bt = ws + OFF_BASET + a * S;
    for (int b = t; b < S; b += 256) {
        float base = (a < 192) ? bt[b] : 0.f;
        out[a * S + b] = __expf(fminf(base - ua - V[b], 0.f));
    }
}

// ---------------------------------------------------------------------------
extern "C" void kernel_launch(void* const* d_in, const int* in_sizes, int n_in,
                              void* d_out, int out_size, void* d_ws, size_t ws_size,
                              hipStream_t stream)
{
    const int*   E1f    = (const int*)d_in[0];
    const int*   E1b    = (const int*)d_in[1];
    const float* cost   = (const float*)d_in[3];
    const float* constr = (const float*)d_in[4];

    float* ws = (float*)d_ws;

    k_setup<<<64, 256, 0, stream>>>(E1f, E1b, cost, constr, ws);

    for (int step = 0; step < 8; ++step) {
        k_phase_a<<<42, 256, 0, stream>>>(ws);
        k_v<<<12, 256, 0, stream>>>(ws);
        k_msg<<<NE, 256, 0, stream>>>(ws, 1);
        k_phase_d<<<48, 256, 0, stream>>>(ws);
        k_msg<<<NE, 256, 0, stream>>>(ws, 0);
        k_scatter_b<<<12, 256, 0, stream>>>(ws);
    }

    k_final<<<S, 256, 0, stream>>>(ws, (float*)d_out);
}

// Round 5
// 250.342 us; speedup vs baseline: 6.8486x; 2.1270x over previous
//
#include <hip/hip_runtime.h>
#include <math.h>

#define S      384
#define N0     192
#define NE     191
#define MAXADJ 16
#define E50    1.9287498e-22f   // exp(-50)

// float workspace offsets
#define OFF_W     0
#define OFF_WT    36864
#define OFF_PHIE  73728
#define OFF_MSGF  147456
#define OFF_MSGB  221184
#define OFF_MXF   294912
#define OFF_MXB   368640
#define OFF_SBT   442368
#define OFF_BASET 516096
#define OFF_U     589824
#define OFF_V     590016
#define OFF_MAXF  590400
#define OFF_MAXB  590592
#define OFF_HIF   590784
#define OFF_LOF   590976
#define OFF_HIB   591168
#define OFF_LOB   591360
#define OFF_UHI   591552
#define OFF_INT   591616
// int offsets relative to (int*)(ws + OFF_INT)
#define IOFF_DSTF 0
#define IOFF_DSTB 192
#define IOFF_CNTF 384
#define IOFF_CNTB 576
#define IOFF_ADJF 768
#define IOFF_ADJB (768 + 192*MAXADJ)

// ---------------------------------------------------------------------------
__global__ __launch_bounds__(256) void k_setup(
    const int* __restrict__ E1f, const int* __restrict__ E1b,
    const float* __restrict__ cost, const float* __restrict__ constr,
    float* __restrict__ ws)
{
    int tid = blockIdx.x * 256 + threadIdx.x;
    int nt  = gridDim.x * 256;

    for (int idx = tid; idx < 192 * 192; idx += nt) {
        int k = idx / 192, s = idx % 192;
        float w = __expf(-50.f * (1.f - constr[idx]));
        ws[OFF_W + idx] = w;               // W[k][s]  (fwd GEMV weights)
        ws[OFF_WT + s * 192 + k] = w;      // WT[k][s] = W[s][k] (bwd)
    }
    for (int idx = tid; idx < 192 * S; idx += nt) {
        int j = idx / S, i = idx % S;
        ws[OFF_PHIE + idx] = (i < N0) ? -10.f * cost[j * N0 + i] : 0.f;
        ws[OFF_MSGF + idx] = 0.f;
        ws[OFF_MSGB + idx] = 0.f;
        ws[OFF_MXF + idx]  = 0.f;
        ws[OFF_MXB + idx]  = (j < NE) ? 1.f : 0.f;   // exp(0-0)=1
    }
    for (int i = tid; i < S; i += nt) ws[OFF_V + i] = 0.f;
    for (int i = tid; i < 192; i += nt) {
        ws[OFF_U + i] = 0.f;
        ws[OFF_MAXF + i] = 0.f; ws[OFF_MAXB + i] = 0.f;
        ws[OFF_HIF + i] = 0.f;  ws[OFF_LOF + i] = 0.f;
        ws[OFF_HIB + i] = (i < NE) ? 192.f : 0.f;
        ws[OFF_LOB + i] = (i < NE) ? 192.f : 0.f;
    }
    if (tid == 0) ws[OFF_UHI] = 0.f;

    int* ip = (int*)(ws + OFF_INT);
    for (int e = tid; e < 192; e += nt) {
        ip[IOFF_DSTF + e] = (e < NE) ? E1f[2 * e + 1] : 0;
        ip[IOFF_DSTB + e] = (e < NE) ? E1b[2 * e + 1] : 0;
    }
    for (int b = tid; b < 192; b += nt) {
        int cf = 0, cb = 0;
        for (int e = 0; e < NE; ++e) {
            if (E1f[2 * e + 1] == b && cf < MAXADJ) ip[IOFF_ADJF + b * MAXADJ + cf++] = e;
            if (E1b[2 * e + 1] == b && cb < MAXADJ) ip[IOFF_ADJB + b * MAXADJ + cb++] = e;
        }
        ip[IOFF_CNTF + b] = cf;
        ip[IOFF_CNTB + b] = cb;
    }
}

// ---------------------------------------------------------------------------
// K1: per row j<192 (one wave each): gather SFT/SBT from msgs, rewrite
//     BASET[j] = -phie[j] + sft + sbt, store SBT[j], compute u[j] = LSE_i(BT-V).
//     Block 48: uhi = LSE_i(-V[i]).
__global__ __launch_bounds__(256) void k_uv1(float* __restrict__ ws)
{
    int bid = blockIdx.x, t = threadIdx.x;
    int l = t & 63, w = t >> 6;
    const float* V = ws + OFF_V;

    if (bid == 48) {
        if (w == 0) {
            float m = -1e30f, x[6];
#pragma unroll
            for (int q = 0; q < 6; ++q) { x[q] = -V[l + 64 * q]; m = fmaxf(m, x[q]); }
#pragma unroll
            for (int o = 32; o; o >>= 1) m = fmaxf(m, __shfl_xor(m, o, 64));
            float sm = 0.f;
#pragma unroll
            for (int q = 0; q < 6; ++q) sm += __expf(x[q] - m);
#pragma unroll
            for (int o = 32; o; o >>= 1) sm += __shfl_xor(sm, o, 64);
            if (l == 0) ws[OFF_UHI] = m + __logf(sm);
        }
        return;
    }

    int j = bid * 4 + w;                    // 48 blocks x 4 waves = 192 rows
    const int* ip = (const int*)(ws + OFF_INT);
    int cF = ip[IOFF_CNTF + j], cB = ip[IOFF_CNTB + j];
    const int* aF = ip + IOFF_ADJF + j * MAXADJ;
    const int* aB = ip + IOFF_ADJB + j * MAXADJ;

    float sft[6] = {0,0,0,0,0,0}, sbt[6] = {0,0,0,0,0,0};
    for (int q = 0; q < cF; ++q) {
        const float* mr = ws + OFF_MSGF + aF[q] * S;
#pragma unroll
        for (int p = 0; p < 6; ++p) sft[p] += mr[l + 64 * p];
    }
    for (int q = 0; q < cB; ++q) {
        const float* mr = ws + OFF_MSGB + aB[q] * S;
#pragma unroll
        for (int p = 0; p < 6; ++p) sbt[p] += mr[l + 64 * p];
    }

    float x[6], m = -1e30f;
#pragma unroll
    for (int p = 0; p < 6; ++p) {
        int i = l + 64 * p;
        float bt = ws[OFF_PHIE + j * S + i] + sft[p] + sbt[p];
        ws[OFF_BASET + j * S + i] = bt;
        ws[OFF_SBT + j * S + i]   = sbt[p];
        x[p] = bt - V[i];
        m = fmaxf(m, x[p]);
    }
#pragma unroll
    for (int o = 32; o; o >>= 1) m = fmaxf(m, __shfl_xor(m, o, 64));
    float sm = 0.f;
#pragma unroll
    for (int p = 0; p < 6; ++p) sm += __expf(x[p] - m);
#pragma unroll
    for (int o = 32; o; o >>= 1) sm += __shfl_xor(sm, o, 64);
    if (l == 0) ws[OFF_U + j] = m + __logf(sm);
}

// K2: v[i] = log( sum_{j<192} exp(BT[j][i]-u[j]) + 192*exp(-uhi) )
//     24 blocks x 16 cols; 16 j-groups online-LSE + LDS combine
__global__ __launch_bounds__(256) void k_v(float* __restrict__ ws)
{
    __shared__ float Ul[192];
    __shared__ float msh[16][17], ssh[16][17];
    int t = threadIdx.x, bid = blockIdx.x;
    if (t < 192) Ul[t] = ws[OFF_U + t];
    __syncthreads();

    const float* BT = ws + OFF_BASET;
    int il = t & 15, jg = t >> 4;
    int i = bid * 16 + il;

    float m = -1e30f, sm = 0.f;
#pragma unroll 4
    for (int j = jg; j < 192; j += 16) {
        float x = BT[j * S + i] - Ul[j];
        float mn = fmaxf(m, x);
        sm = sm * __expf(m - mn) + __expf(x - mn);
        m = mn;
    }
    msh[jg][il] = m; ssh[jg][il] = sm;
    __syncthreads();

    if (jg == 0) {
        float M = msh[0][il], Ss = ssh[0][il];
#pragma unroll
        for (int g = 1; g < 16; ++g) {
            float m2 = msh[g][il], s2 = ssh[g][il];
            float mn = fmaxf(M, m2);
            Ss = Ss * __expf(M - mn) + s2 * __expf(m2 - mn);
            M = mn;
        }
        float xt = __logf(192.f) - ws[OFF_UHI];
        float mn = fmaxf(M, xt);
        Ss = Ss * __expf(M - mn) + __expf(xt - mn);
        ws[OFF_V + i] = mn + __logf(Ss);
    }
}

// K3/K4: msg update with fused GEMV + colsum. One block per edge.
//  fwd: y_lo[s] = sum_k W[k][s]*MXB[e][k] ; bt = BASET[d]
//  bwd: y_lo[s] = sum_k WT[k][s]*MXF[e][k]; bt = PHIE[d]+SBT[d]+gather(MSGF,adjF[d])
__global__ __launch_bounds__(256) void k_msg(float* __restrict__ ws, int fwd)
{
    __shared__ float mx[192];
    __shared__ float red[256], red2[256];
    int e = blockIdx.x, t = threadIdx.x;
    const int* ip = (const int*)(ws + OFF_INT);

    float* MSG  = ws + (fwd ? OFF_MSGF : OFF_MSGB);
    float* MX   = ws + (fwd ? OFF_MXF  : OFF_MXB);
    const float* MXin = ws + (fwd ? OFF_MXB : OFF_MXF);
    const float* Wm   = ws + (fwd ? OFF_W   : OFF_WT);

    float mPrev = fwd ? ws[OFF_MAXB + e] : ws[OFF_MAXF + e];
    float hi    = fwd ? ws[OFF_HIB + e]  : ws[OFF_HIF + e];
    float lo    = fwd ? ws[OFF_LOB + e]  : ws[OFF_LOF + e];
    float addLo = fwd ? hi : E50 * hi;
    float yHi   = fwd ? (hi + E50 * lo) : (lo + hi);
    float lyHi  = __logf(yHi);

    int d = fwd ? ip[IOFF_DSTF + e] : ip[IOFF_DSTB + e];
    float uD = ws[OFF_U + d];
    const float* V = ws + OFF_V;

    if (t < 192) mx[t] = MXin[e * S + t];
    __syncthreads();

    // GEMV: y = sum_k Wm[k][s] * mx[k], thread t owns s=t (t<192)
    float acc = 0.f;
    if (t < 192) {
#pragma unroll 8
        for (int k = 0; k < 192; ++k)
            acc += Wm[k * 192 + t] * mx[k];
    }

    // bt for this thread's two columns
    int s1 = t, s2 = t + 256;
    float bt1, bt2 = 0.f;
    if (fwd) {
        bt1 = ws[OFF_BASET + d * S + s1];
        if (s2 < S) bt2 = ws[OFF_BASET + d * S + s2];
    } else {
        int cF = ip[IOFF_CNTF + d];
        const int* aF = ip + IOFF_ADJF + d * MAXADJ;
        bt1 = ws[OFF_PHIE + d * S + s1] + ws[OFF_SBT + d * S + s1];
        if (s2 < S) bt2 = ws[OFF_PHIE + d * S + s2] + ws[OFF_SBT + d * S + s2];
        for (int q = 0; q < cF; ++q) {
            const float* mr = ws + OFF_MSGF + aF[q] * S;
            bt1 += mr[s1];
            if (s2 < S) bt2 += mr[s2];
        }
    }

    float logy1 = (s1 < 192) ? __logf(acc + addLo) : lyHi;
    float x1 = 0.5f * (MSG[e * S + s1] + uD + V[s1] - bt1 + mPrev + logy1);
    float x2 = 1e30f;
    if (s2 < S) {
        x2 = 0.5f * (MSG[e * S + s2] + uD + V[s2] - bt2 + mPrev + lyHi);
        MSG[e * S + s2] = x2;
    }
    MSG[e * S + s1] = x1;

    red[t] = fminf(x1, x2);
    __syncthreads();
    for (int o = 128; o; o >>= 1) {
        if (t < o) red[t] = fminf(red[t], red[t + o]);
        __syncthreads();
    }
    float mn = red[0];
    __syncthreads();

    float mx1 = __expf(mn - x1);
    float mx2 = (s2 < S) ? __expf(mn - x2) : 0.f;
    MX[e * S + s1] = mx1;
    if (s2 < S) MX[e * S + s2] = mx2;
    if (t == 0) {
        if (fwd) ws[OFF_MAXF + e] = -mn; else ws[OFF_MAXB + e] = -mn;
    }

    red[t]  = (t < 192) ? mx1 : 0.f;
    red2[t] = ((t >= 192) ? mx1 : 0.f) + mx2;
    __syncthreads();
    for (int o = 128; o; o >>= 1) {
        if (t < o) { red[t] += red[t + o]; red2[t] += red2[t + o]; }
        __syncthreads();
    }
    if (t == 0) {
        if (fwd) { ws[OFF_LOF + e] = red[0]; ws[OFF_HIF + e] = red2[0]; }
        else     { ws[OFF_LOB + e] = red[0]; ws[OFF_HIB + e] = red2[0]; }
    }
}

// final: out[a][b] = exp(min(btFinal[a][b] - U[a] - V[b], 0))
//   btFinal = phie + gather(MSGF) + gather(MSGB); rows a>=192: bt=0, U=uhi
__global__ __launch_bounds__(256) void k_final(const float* __restrict__ ws,
                                               float* __restrict__ out)
{
    int t = threadIdx.x;
    const int* ip = (const int*)(ws + OFF_INT);
    const float* V = ws + OFF_V;
    float uhi = ws[OFF_UHI];

    for (int a = blockIdx.x * 6; a < blockIdx.x * 6 + 6; ++a) {
        if (a < 192) {
            float ua = ws[OFF_U + a];
            int cF = ip[IOFF_CNTF + a], cB = ip[IOFF_CNTB + a];
            const int* aF = ip + IOFF_ADJF + a * MAXADJ;
            const int* aB = ip + IOFF_ADJB + a * MAXADJ;
            for (int b = t; b < S; b += 256) {
                float bt = ws[OFF_PHIE + a * S + b];
                for (int q = 0; q < cF; ++q) bt += ws[OFF_MSGF + aF[q] * S + b];
                for (int q = 0; q < cB; ++q) bt += ws[OFF_MSGB + aB[q] * S + b];
                out[a * S + b] = __expf(fminf(bt - ua - V[b], 0.f));
            }
        } else {
            for (int b = t; b < S; b += 256)
                out[a * S + b] = __expf(fminf(-uhi - V[b], 0.f));
        }
    }
}

// ---------------------------------------------------------------------------
extern "C" void kernel_launch(void* const* d_in, const int* in_sizes, int n_in,
                              void* d_out, int out_size, void* d_ws, size_t ws_size,
                              hipStream_t stream)
{
    const int*   E1f    = (const int*)d_in[0];
    const int*   E1b    = (const int*)d_in[1];
    const float* cost   = (const float*)d_in[3];
    const float* constr = (const float*)d_in[4];

    float* ws = (float*)d_ws;

    k_setup<<<64, 256, 0, stream>>>(E1f, E1b, cost, constr, ws);

    for (int step = 0; step < 8; ++step) {
        k_uv1<<<49, 256, 0, stream>>>(ws);
        k_v<<<24, 256, 0, stream>>>(ws);
        k_msg<<<NE, 256, 0, stream>>>(ws, 1);
        k_msg<<<NE, 256, 0, stream>>>(ws, 0);
    }

    k_final<<<64, 256, 0, stream>>>(ws, (float*)d_out);
}